// Round 4
// baseline (143.103 us; speedup 1.0000x reference)
//
#include <hip/hip_runtime.h>
#include <hip/hip_bf16.h>

// out = Re[(Fr + i Fi) @ U] as float32[65536,128] (out_size = 8388608 floats).
// U = Clements mesh (128 layers of disjoint 2x2 MZI column rotations) * diag(e^{i oph}).
//
// R11: prelude consolidation. Budget: ~98us fixed poison fills + ~17us BW-bound
// cgemm (R8/R10 latency fixes both null => cgemm at floor) + ~8us prelude.
// trig_k merged into build_u2: 128 blocks x 256 thr; phase 1 computes the full
// 8192-entry trig table into 128KB dynamic LDS in parallel (same sincosf bits,
// same op order => U identical, absmax unchanged); phase 2 wave 0 runs the
// 128-layer chain with its depth-8 ring read from LDS. 3 launches -> 2.
//   k1 build_u2: 128 blocks x 256 thr, 128KB dyn LDS; wave 0 evolves ROW r of U
//                in registers (lane p owns cols 2p,2p+1; odd layers shfl).
//   k2 cgemm:    512 blocks x 256 thr (4 waves x 32 rows), N=K=128, bf16 MFMA,
//                Re = Fr*Ur - Fi*Ui; U frags LDS-resident (64 KB); kt01 A direct
//                + kt23 touch-prefetch (R10, harmless under flushed L3).

typedef __attribute__((ext_vector_type(8))) short short8;
typedef __attribute__((ext_vector_type(4))) float float4v;

#define MFMA(a, b, c) __builtin_amdgcn_mfma_f32_16x16x32_bf16((a), (b), (c), 0, 0, 0)

__device__ __forceinline__ unsigned short f2bf(float f) {
    unsigned u = __builtin_bit_cast(unsigned, f);
    u += 0x7FFFu + ((u >> 16) & 1u);   // round-to-nearest-even
    return (unsigned short)(u >> 16);
}

__device__ __forceinline__ short bf(float x) {
    return __bfloat16_as_short(__float2bfloat16(x));   // RNE, cvt_pk-fusable
}

__device__ __forceinline__ short8 pack8(float4v a, float4v b) {
    short8 r;
    r[0] = bf(a[0]); r[1] = bf(a[1]); r[2] = bf(a[2]); r[3] = bf(a[3]);
    r[4] = bf(b[0]); r[5] = bf(b[1]); r[6] = bf(b[2]); r[7] = bf(b[3]);
    return r;
}

__device__ __forceinline__ short8 pack8n(float4v a, float4v b) {  // negated
    short8 r;
    r[0] = bf(-a[0]); r[1] = bf(-a[1]); r[2] = bf(-a[2]); r[3] = bf(-a[3]);
    r[4] = bf(-b[0]); r[5] = bf(-b[1]); r[6] = bf(-b[2]); r[7] = bf(-b[3]);
    return r;
}

// Issue a 4B load to warm the cache line holding p (R10 infra; kept).
__device__ __forceinline__ float touch_line(const void* p) {
    float r;
    asm volatile("global_load_dword %0, %1, off" : "=v"(r) : "v"(p));
    return r;
}

// ---------------- Kernel 1: trig table (parallel) + build U (wave 0) ----------
// MZI id for (layer l, pair p): (127*l + (l&1))/2 + p   (max 8128 -> padded tbl)
__global__ __launch_bounds__(256) void build_u2(
    const float* __restrict__ oph, const float* __restrict__ mzi,
    unsigned short* ufrag /* 2 copies x 2 planes x 16384 bf16, frag order */) {
    extern __shared__ __align__(16) float4 ltrig[];   // 8192 x 16B = 128 KB
    const int r = blockIdx.x;    // row of U this block owns
    const int tid = threadIdx.x;

    // Phase 1: all 256 threads fill the trig table (same sincosf as trig_k).
    #pragma unroll
    for (int base = 0; base < 8192; base += 256) {
        const int id = base + tid;
        if (id < 8128) {
            const float theta = mzi[2 * id], phi = mzi[2 * id + 1];
            float st, ct, sp, cp;
            sincosf(theta, &st, &ct);
            sincosf(phi, &sp, &cp);
            ltrig[id] = make_float4(ct * cp, ct * sp, st, 0.f);
        } else {
            ltrig[id] = make_float4(0.f, 0.f, 0.f, 0.f);  // pad (ring in-bounds)
        }
    }
    __syncthreads();

    // Phase 2: wave 0 evolves row r across the 128 layers (identical chain).
    if (tid >= 64) return;
    const int p = tid;           // lane: owns cols 2p, 2p+1
    float2 c0 = make_float2((2 * p == r) ? 1.f : 0.f, 0.f);
    float2 c1 = make_float2((2 * p + 1 == r) ? 1.f : 0.f, 0.f);

    float4 ring[8];
    #pragma unroll
    for (int i = 0; i < 8; ++i)
        ring[i] = ltrig[(127 * i + (i & 1)) / 2 + p];

    #pragma unroll   // FULL unroll: ring indices constant -> ring stays in VGPRs
    for (int l = 0; l < 128; ++l) {
        const float4 t = ring[l & 7];
        if (l + 8 < 128)
            ring[l & 7] = ltrig[(127 * (l + 8) + ((l + 8) & 1)) / 2 + p];
        const float ar = t.x, ai = t.y, s = t.z;
        if ((l & 1) == 0) {
            // pair (2p, 2p+1) = (c0, c1), fully local
            const float2 u = c0, v = c1;
            c0.x = u.x * ar - u.y * ai + v.x * s;
            c0.y = u.x * ai + u.y * ar + v.y * s;
            c1.x = u.x * s - v.x * ar - v.y * ai;
            c1.y = u.y * s + v.x * ai - v.y * ar;
        } else {
            // pair q=p: cols (2p+1, 2p+2) = (my c1, lane p+1's c0)
            const float vx = __shfl_down(c0.x, 1);
            const float vy = __shfl_down(c0.y, 1);
            const float2 u = c1;
            const float nux = u.x * ar - u.y * ai + vx * s;
            const float nuy = u.x * ai + u.y * ar + vy * s;
            const float nvx = u.x * s - vx * ar - vy * ai;
            const float nvy = u.y * s + vx * ai - vy * ar;
            if (p < 63) { c1.x = nux; c1.y = nuy; }   // col 2p+1 update
            const float bx = __shfl_up(nvx, 1);       // col 2p+2 -> lane p+1's c0
            const float by = __shfl_up(nvy, 1);
            if (p > 0) { c0.x = bx; c0.y = by; }      // lane 0 keeps col 0
        }
    }

    // output-phase diagonal + bf16 + scatter into MFMA B-fragment order:
    // B[k][n]: nt=j>>4, lane=(j&15)|(((k>>3)&3)<<4), elem=k&7, kt=k>>5 (k=r,n=j)
    #pragma unroll
    for (int jj = 0; jj < 2; ++jj) {
        const int j = 2 * p + jj;
        const float2 v = (jj == 0) ? c0 : c1;
        float s, c;
        sincosf(oph[j], &s, &c);
        const unsigned short re = f2bf(v.x * c - v.y * s);
        const unsigned short im = f2bf(v.x * s + v.y * c);
        const int nt = j >> 4, kt = r >> 5;
        const int lane = (j & 15) | (((r >> 3) & 3) << 4);
        const int base = (nt * 4 + kt) * 512 + lane * 8 + (r & 7);
        ufrag[base]          = re;   // copy A, plane R
        ufrag[16384 + base]  = im;   // copy A, plane I
        ufrag[32768 + base]  = re;   // copy B, plane R
        ufrag[49152 + base]  = im;   // copy B, plane I
    }
}

// --------- 128-row tile, real-part GEMM (4 waves x 32 rows, N=K=128) ---------
__device__ __forceinline__ void gemm128(
    const float* __restrict__ fr, const float* __restrict__ fi,
    const unsigned short* ufcopy, float* out, int tilebase, int maxrow) {
    __shared__ __align__(16) unsigned short us[32768];  // 64 KB: Ur | Ui frags
    const int tid = threadIdx.x;
    const int wave = tid >> 6, lane = tid & 63;
    const int lm = lane & 15, lq = lane >> 4;
    const int rowbase = tilebase + wave * 32;

    const size_t abase = (size_t)(rowbase + lm) * 128 + lq * 8;
    const float* pfr = fr + abase;   // mt adds 16 rows = +2048 floats
    const float* pfi = fi + abase;

    // Phase 0a: direct A loads for kt=0,1 (needed first post-barrier).
    float4v sr[2][2][2], si[2][2][2];   // [ktbuf][mt][half]
    #pragma unroll
    for (int b = 0; b < 2; ++b) {
        #pragma unroll
        for (int mt = 0; mt < 2; ++mt) {
            sr[b][mt][0] = *(const float4v*)(pfr + b * 32 + mt * 2048);
            sr[b][mt][1] = *(const float4v*)(pfr + b * 32 + mt * 2048 + 4);
            si[b][mt][0] = *(const float4v*)(pfi + b * 32 + mt * 2048);
            si[b][mt][1] = *(const float4v*)(pfi + b * 32 + mt * 2048 + 4);
        }
    }

    // Phase 0b: touch-prefetch the kt2/3 A region into L2 (one 4B load per
    // 64B line; 64KB/block in flight from 16B of VGPR).
    float tch[4];
    #pragma unroll
    for (int i = 0; i < 2; ++i) {
        const int l = tid + 256 * i;
        const size_t off = (size_t)(tilebase + (l >> 2)) * 512 + 256 + (size_t)(l & 3) * 64;
        tch[i]     = touch_line((const char*)fr + off);
        tch[2 + i] = touch_line((const char*)fi + off);
    }

    // Phase 1: 64 KB global -> LDS: 256 thr x 16 iter x 16 B (linear dest).
#if __has_builtin(__builtin_amdgcn_global_load_lds)
    {
        const unsigned int* g = (const unsigned int*)ufcopy;
        auto* gsrc = (const __attribute__((address_space(1))) unsigned int*)(const void*)g;
        auto* ldst = (__attribute__((address_space(3))) unsigned int*)(void*)&us[0];
        #pragma unroll
        for (int i = 0; i < 16; ++i)
            __builtin_amdgcn_global_load_lds(gsrc + 4 * (tid + 256 * i),
                                             ldst + 4 * (tid + 256 * i), 16, 0, 0);
    }
#else
    {
        const uint4* g = (const uint4*)ufcopy;
        uint4* l = (uint4*)us;
        #pragma unroll
        for (int i = 0; i < 16; ++i) l[tid + 256 * i] = g[tid + 256 * i];
    }
#endif
    __syncthreads();   // compiler drains vmcnt(0) here -> touches retired

    // Keep touch dests alive past the barrier's vmcnt(0) drain.
    asm volatile("" :: "v"(tch[0]), "v"(tch[1]), "v"(tch[2]), "v"(tch[3]));

    float4v accR[2][8] = {};

    #pragma unroll
    for (int kt = 0; kt < 4; ++kt) {
        const int b = kt & 1;   // compile-time (full unroll)
        short8 afr[2], afin[2];
        #pragma unroll
        for (int mt = 0; mt < 2; ++mt) {
            afr[mt]  = pack8 (sr[b][mt][0], sr[b][mt][1]);
            afin[mt] = pack8n(si[b][mt][0], si[b][mt][1]);  // -Fi via float neg
        }
        if (kt < 2) {  // refill buffer b with kt+2 (L2-hit: lines touched)
            #pragma unroll
            for (int mt = 0; mt < 2; ++mt) {
                sr[b][mt][0] = *(const float4v*)(pfr + (kt + 2) * 32 + mt * 2048);
                sr[b][mt][1] = *(const float4v*)(pfr + (kt + 2) * 32 + mt * 2048 + 4);
                si[b][mt][0] = *(const float4v*)(pfi + (kt + 2) * 32 + mt * 2048);
                si[b][mt][1] = *(const float4v*)(pfi + (kt + 2) * 32 + mt * 2048 + 4);
            }
        }
        #pragma unroll
        for (int nt = 0; nt < 8; ++nt) {
            const int fo = (nt * 4 + kt) * 512 + lane * 8;
            const short8 ur = *(const short8*)&us[fo];
            const short8 ui = *(const short8*)&us[16384 + fo];
            #pragma unroll
            for (int mt = 0; mt < 2; ++mt) {
                accR[mt][nt] = MFMA(afr[mt],  ur, accR[mt][nt]);
                accR[mt][nt] = MFMA(afin[mt], ui, accR[mt][nt]);
            }
        }
    }

    // epilogue: D layout col = lane&15, row = (lane>>4)*4 + reg — GUARDED
    // (each 16-lane group writes one full 64B line: coalescing already ideal)
    #pragma unroll
    for (int mt = 0; mt < 2; ++mt) {
        #pragma unroll
        for (int nt = 0; nt < 8; ++nt) {
            #pragma unroll
            for (int reg = 0; reg < 4; ++reg) {
                const int rr = rowbase + mt * 16 + lq * 4 + reg;
                if (rr < maxrow)
                    out[(size_t)rr * 128 + nt * 16 + lm] = accR[mt][nt][reg];
            }
        }
    }
}

__global__ __launch_bounds__(256, 2) void cgemm_main(
    const float* __restrict__ fr, const float* __restrict__ fi,
    const unsigned short* ufrag, float* out, int maxrow, int rowoff) {
    gemm128(fr, fi, ufrag, out, rowoff + blockIdx.x * 128, maxrow);  // copy A
}

__global__ __launch_bounds__(256, 2) void cgemm_tail(
    const float* __restrict__ fr, const float* __restrict__ fi,
    const unsigned short* ufrag, float* out, int maxrow) {
    // fallback path only: block b reads copy b, overwrites exactly its region
    gemm128(fr, fi, ufrag + blockIdx.x * 32768, out, blockIdx.x * 128, maxrow);
}

extern "C" void kernel_launch(void* const* d_in, const int* in_sizes, int n_in,
                              void* d_out, int out_size, void* d_ws, size_t ws_size,
                              hipStream_t stream) {
    const float* fr  = (const float*)d_in[0];
    const float* fi  = (const float*)d_in[1];
    const float* mzi = (const float*)d_in[2];
    const float* oph = (const float*)d_in[3];

    // Capacity in 128-float output rows; clamp by field rows (A-load safety).
    int maxrow = out_size / 128;
    const int arows = in_sizes[0] / 128;
    if (maxrow > arows) maxrow = arows;
    if (maxrow > 65536) maxrow = 65536;

    if (ws_size >= 131072) {
        // Preferred: ufrag (2 copies, 128 KB) in d_ws. No tail kernel.
        unsigned short* ufrag = (unsigned short*)d_ws;
        if (maxrow < 1) return;
        build_u2<<<128, 256, 131072, stream>>>(oph, mzi, ufrag);
        const int nblk = (maxrow + 127) / 128;
        cgemm_main<<<nblk, 256, 0, stream>>>(fr, fi, ufrag, (float*)d_out,
                                             maxrow, 0);
    } else {
        // Fallback: stage ufrag inside d_out rows 0..255 (proven path).
        unsigned short* ufrag = (unsigned short*)d_out;
        if (maxrow < 512) return;
        build_u2<<<128, 256, 131072, stream>>>(oph, mzi, ufrag);
        const int nmain = (maxrow - 256 + 127) / 128;
        cgemm_main<<<nmain, 256, 0, stream>>>(fr, fi, ufrag, (float*)d_out,
                                              maxrow, 256);
        cgemm_tail<<<2, 256, 0, stream>>>(fr, fi, ufrag, (float*)d_out, maxrow);
    }
}

// Round 5
// 121.387 us; speedup vs baseline: 1.1789x; 1.1789x over previous
//
#include <hip/hip_runtime.h>

// out = Re[(Fr + i Fi) @ U] as float32[65536,128] (out_size = 8388608 floats).
// U = Clements mesh (128 layers of disjoint 2x2 MZI column rotations) * diag(e^{i oph}).
// R12 = revert to R0/R7 baseline (best measured: 121.87us). Post-mortem trail:
//   R8  (reg-prefetch depth 2, cvt_pk pack, glds staging): null (122.36)
//   R9  (cooperative fusion, inline serial sincosf build):  +2us, MfmaUtil 0.9%
//   R10 (L2 touch-prefetch of kt2/3 A lines):               null (122.66)
//   R11 (trig merged into build, 128x redundant sincosf):   +21us (143.1)
// Budget: ~89us poison fills (untouchable, write-BW ceiling) + ~17us cgemm at
// traffic floor (two latency theories falsified, zero over-fetch) + ~8us
// prelude (two fusion attempts regressed). At harness+BW roofline.
//   k0 trig_k:   8128 MZIs -> (ct*cp, ct*sp, st) float4; pad to 8192.
//   k1 build_u:  128 blocks x 1 wave; block r evolves ROW r of U in registers
//                (lane p owns cols 2p,2p+1; odd layers shfl-exchange neighbor col;
//                depth-8 trig ring, FULL unroll keeps ring in VGPRs).
//   k2 cgemm:    512 blocks x 256 thr (4 waves x 32 rows), N=K=128, bf16 MFMA,
//                Re = Fr*Ur - Fi*Ui; U frags LDS-resident (64 KB).

typedef __attribute__((ext_vector_type(8))) short short8;
typedef __attribute__((ext_vector_type(4))) float float4v;

#define MFMA(a, b, c) __builtin_amdgcn_mfma_f32_16x16x32_bf16((a), (b), (c), 0, 0, 0)

__device__ __forceinline__ unsigned short f2bf(float f) {
    unsigned u = __builtin_bit_cast(unsigned, f);
    u += 0x7FFFu + ((u >> 16) & 1u);   // round-to-nearest-even
    return (unsigned short)(u >> 16);
}

__device__ __forceinline__ short8 pack8(float4v a, float4v b) {
    short8 r;
    r[0] = (short)f2bf(a[0]); r[1] = (short)f2bf(a[1]);
    r[2] = (short)f2bf(a[2]); r[3] = (short)f2bf(a[3]);
    r[4] = (short)f2bf(b[0]); r[5] = (short)f2bf(b[1]);
    r[6] = (short)f2bf(b[2]); r[7] = (short)f2bf(b[3]);
    return r;
}

// ---------------- Kernel 0: per-MZI trig (fully parallel) ----------------
__global__ __launch_bounds__(256) void trig_k(const float* __restrict__ mzi,
                                              float4* __restrict__ trig) {
    const int id = blockIdx.x * 256 + threadIdx.x;
    if (id >= 8192) return;
    if (id < 8128) {
        const float theta = mzi[2 * id], phi = mzi[2 * id + 1];
        float st, ct, sp, cp;
        sincosf(theta, &st, &ct);
        sincosf(phi, &sp, &cp);
        trig[id] = make_float4(ct * cp, ct * sp, st, 0.f);
    } else {
        trig[id] = make_float4(0.f, 0.f, 0.f, 0.f);  // pad (ring loads in-bounds)
    }
}

// ---------------- Kernel 1: build U, one block (1 wave) per row ----------------
// MZI id for (layer l, pair p): (127*l + (l&1))/2 + p   (max 8128 -> padded buf)
__global__ __launch_bounds__(64) void build_u(
    const float* __restrict__ oph, const float4* __restrict__ trig,
    unsigned short* ufrag /* 2 copies x 2 planes x 16384 bf16, frag order */) {
    const int r = blockIdx.x;   // row of U this block owns
    const int p = threadIdx.x;  // lane: owns cols 2p, 2p+1
    float2 c0 = make_float2((2 * p == r) ? 1.f : 0.f, 0.f);
    float2 c1 = make_float2((2 * p + 1 == r) ? 1.f : 0.f, 0.f);

    float4 ring[8];
    #pragma unroll
    for (int i = 0; i < 8; ++i)
        ring[i] = trig[(127 * i + (i & 1)) / 2 + p];

    #pragma unroll   // FULL unroll: ring indices constant -> ring stays in VGPRs
    for (int l = 0; l < 128; ++l) {
        const float4 t = ring[l & 7];
        if (l + 8 < 128)
            ring[l & 7] = trig[(127 * (l + 8) + ((l + 8) & 1)) / 2 + p];
        const float ar = t.x, ai = t.y, s = t.z;
        if ((l & 1) == 0) {
            // pair (2p, 2p+1) = (c0, c1), fully local
            const float2 u = c0, v = c1;
            c0.x = u.x * ar - u.y * ai + v.x * s;
            c0.y = u.x * ai + u.y * ar + v.y * s;
            c1.x = u.x * s - v.x * ar - v.y * ai;
            c1.y = u.y * s + v.x * ai - v.y * ar;
        } else {
            // pair q=p: cols (2p+1, 2p+2) = (my c1, lane p+1's c0)
            const float vx = __shfl_down(c0.x, 1);
            const float vy = __shfl_down(c0.y, 1);
            const float2 u = c1;
            const float nux = u.x * ar - u.y * ai + vx * s;
            const float nuy = u.x * ai + u.y * ar + vy * s;
            const float nvx = u.x * s - vx * ar - vy * ai;
            const float nvy = u.y * s + vx * ai - vy * ar;
            if (p < 63) { c1.x = nux; c1.y = nuy; }   // col 2p+1 update
            const float bx = __shfl_up(nvx, 1);       // col 2p+2 -> lane p+1's c0
            const float by = __shfl_up(nvy, 1);
            if (p > 0) { c0.x = bx; c0.y = by; }      // lane 0 keeps col 0
        }
    }

    // output-phase diagonal + bf16 + scatter into MFMA B-fragment order:
    // B[k][n]: nt=j>>4, lane=(j&15)|(((k>>3)&3)<<4), elem=k&7, kt=k>>5 (k=r,n=j)
    #pragma unroll
    for (int jj = 0; jj < 2; ++jj) {
        const int j = 2 * p + jj;
        const float2 v = (jj == 0) ? c0 : c1;
        float s, c;
        sincosf(oph[j], &s, &c);
        const unsigned short re = f2bf(v.x * c - v.y * s);
        const unsigned short im = f2bf(v.x * s + v.y * c);
        const int nt = j >> 4, kt = r >> 5;
        const int lane = (j & 15) | (((r >> 3) & 3) << 4);
        const int base = (nt * 4 + kt) * 512 + lane * 8 + (r & 7);
        ufrag[base]          = re;   // copy A, plane R
        ufrag[16384 + base]  = im;   // copy A, plane I
        ufrag[32768 + base]  = re;   // copy B, plane R
        ufrag[49152 + base]  = im;   // copy B, plane I
    }
}

// --------- 128-row tile, real-part GEMM (4 waves x 32 rows, N=K=128) ---------
__device__ __forceinline__ void gemm128(
    const float* __restrict__ fr, const float* __restrict__ fi,
    const unsigned short* ufcopy, float* out, int tilebase, int maxrow) {
    __shared__ __align__(16) unsigned short us[32768];  // 64 KB: Ur | Ui frags
    const int tid = threadIdx.x;
    {   // 64 KB global -> LDS: 256 thr x 16 iter x 16 B
        const uint4* g = (const uint4*)ufcopy;
        uint4* l = (uint4*)us;
        #pragma unroll
        for (int i = 0; i < 16; ++i) l[tid + 256 * i] = g[tid + 256 * i];
    }
    __syncthreads();

    const int wave = tid >> 6, lane = tid & 63;
    const int lm = lane & 15, lq = lane >> 4;
    const int rowbase = tilebase + wave * 32;

    float4v accR[2][8] = {};

    const size_t abase = (size_t)(rowbase + lm) * 128 + lq * 8;
    const float* pfr = fr + abase;   // mt adds 16 rows = +2048 floats
    const float* pfi = fi + abase;

    const short sgn = (short)0x8000;
    const short8 sgn8 = {sgn, sgn, sgn, sgn, sgn, sgn, sgn, sgn};

    float4v sr[2][2], si[2][2];
    #pragma unroll
    for (int mt = 0; mt < 2; ++mt) {
        sr[mt][0] = *(const float4v*)(pfr + mt * 2048);
        sr[mt][1] = *(const float4v*)(pfr + mt * 2048 + 4);
        si[mt][0] = *(const float4v*)(pfi + mt * 2048);
        si[mt][1] = *(const float4v*)(pfi + mt * 2048 + 4);
    }

    #pragma unroll
    for (int kt = 0; kt < 4; ++kt) {
        short8 afr[2], afin[2];
        #pragma unroll
        for (int mt = 0; mt < 2; ++mt) {
            afr[mt]  = pack8(sr[mt][0], sr[mt][1]);
            afin[mt] = pack8(si[mt][0], si[mt][1]) ^ sgn8;  // -Fi sign flip
        }
        if (kt < 3) {  // prefetch next k-tile while MFMAs run
            #pragma unroll
            for (int mt = 0; mt < 2; ++mt) {
                sr[mt][0] = *(const float4v*)(pfr + (kt + 1) * 32 + mt * 2048);
                sr[mt][1] = *(const float4v*)(pfr + (kt + 1) * 32 + mt * 2048 + 4);
                si[mt][0] = *(const float4v*)(pfi + (kt + 1) * 32 + mt * 2048);
                si[mt][1] = *(const float4v*)(pfi + (kt + 1) * 32 + mt * 2048 + 4);
            }
        }
        #pragma unroll
        for (int nt = 0; nt < 8; ++nt) {
            const int fo = (nt * 4 + kt) * 512 + lane * 8;
            const short8 ur = *(const short8*)&us[fo];
            const short8 ui = *(const short8*)&us[16384 + fo];
            #pragma unroll
            for (int mt = 0; mt < 2; ++mt) {
                accR[mt][nt] = MFMA(afr[mt],  ur, accR[mt][nt]);
                accR[mt][nt] = MFMA(afin[mt], ui, accR[mt][nt]);
            }
        }
    }

    // epilogue: D layout col = lane&15, row = (lane>>4)*4 + reg — GUARDED
    #pragma unroll
    for (int mt = 0; mt < 2; ++mt) {
        #pragma unroll
        for (int nt = 0; nt < 8; ++nt) {
            #pragma unroll
            for (int reg = 0; reg < 4; ++reg) {
                const int rr = rowbase + mt * 16 + lq * 4 + reg;
                if (rr < maxrow)
                    out[(size_t)rr * 128 + nt * 16 + lm] = accR[mt][nt][reg];
            }
        }
    }
}

__global__ __launch_bounds__(256, 2) void cgemm_main(
    const float* __restrict__ fr, const float* __restrict__ fi,
    const unsigned short* ufrag, float* out, int maxrow, int rowoff) {
    gemm128(fr, fi, ufrag, out, rowoff + blockIdx.x * 128, maxrow);  // copy A
}

__global__ __launch_bounds__(256, 2) void cgemm_tail(
    const float* __restrict__ fr, const float* __restrict__ fi,
    const unsigned short* ufrag, float* out, int maxrow) {
    // fallback path only: block b reads copy b, overwrites exactly its region
    gemm128(fr, fi, ufrag + blockIdx.x * 32768, out, blockIdx.x * 128, maxrow);
}

extern "C" void kernel_launch(void* const* d_in, const int* in_sizes, int n_in,
                              void* d_out, int out_size, void* d_ws, size_t ws_size,
                              hipStream_t stream) {
    const float* fr  = (const float*)d_in[0];
    const float* fi  = (const float*)d_in[1];
    const float* mzi = (const float*)d_in[2];
    const float* oph = (const float*)d_in[3];

    // Capacity in 128-float output rows; clamp by field rows (A-load safety).
    int maxrow = out_size / 128;
    const int arows = in_sizes[0] / 128;
    if (maxrow > arows) maxrow = arows;
    if (maxrow > 65536) maxrow = 65536;

    if (ws_size >= 262144) {
        // Preferred: stage in d_ws. No tail kernel.
        unsigned short* ufrag = (unsigned short*)d_ws;           // 128 KB (2 copies)
        float4* trig = (float4*)((char*)d_ws + 131072);          // 128 KB
        if (maxrow < 1) return;
        trig_k<<<32, 256, 0, stream>>>(mzi, trig);
        build_u<<<128, 64, 0, stream>>>(oph, trig, ufrag);
        const int nblk = (maxrow + 127) / 128;
        cgemm_main<<<nblk, 256, 0, stream>>>(fr, fi, ufrag, (float*)d_out,
                                             maxrow, 0);
    } else {
        // Fallback: stage inside d_out rows 0..511 (proven path).
        unsigned short* ufrag = (unsigned short*)d_out;          // rows 0..255
        float4* trig = (float4*)((float*)d_out + 32768);         // rows 256..511
        if (maxrow < 512) return;
        trig_k<<<32, 256, 0, stream>>>(mzi, trig);
        build_u<<<128, 64, 0, stream>>>(oph, trig, ufrag);
        const int nmain = (maxrow - 256 + 127) / 128;
        cgemm_main<<<nmain, 256, 0, stream>>>(fr, fi, ufrag, (float*)d_out,
                                              maxrow, 256);
        cgemm_tail<<<2, 256, 0, stream>>>(fr, fi, ufrag, (float*)d_out, maxrow);
    }
}